// Round 1
// baseline (55525.244 us; speedup 1.0000x reference)
//
#include <hip/hip_runtime.h>
#include <hip/hip_cooperative_groups.h>

namespace cg = cooperative_groups;

#define VOCAB 32000
#define EMBED 1024
#define HID   1024
#define BATCH 64
#define SEQ   512
#define R4    4096   // 4*HID, gate rows (i,f,g,o)

// ---------------------------------------------------------------------------
// Phase A: gx[s][r][b] = emb[seq[b][s]] . W_ih[r] + b_ih[r] + b_hh[r]
// Layout [S][4096][64] so the sequential phase reads lanes-coalesced along b.
// grid (16, 512): blockIdx.x = r-tile (256 rows), blockIdx.y = s. Block covers
// all 64 batch rows. Thread tile 4b x 16r, K-chunks of 32, LDS-staged fp32.
// ---------------------------------------------------------------------------
__global__ __launch_bounds__(256) void gates_x_kernel(
    const float* __restrict__ emb, const float* __restrict__ Wih,
    const float* __restrict__ bih, const float* __restrict__ bhh,
    const int* __restrict__ seq, float* __restrict__ gx)
{
    __shared__ float als[64 * 36];    // A tile: 64 b-rows x 32 k, stride 36 (quad-balanced)
    __shared__ float bls[256 * 36];   // B tile: 256 r-rows x 32 k
    __shared__ int   tok[64];

    const int tid = threadIdx.x;
    const int s   = blockIdx.y;
    const int r0  = blockIdx.x * 256;

    if (tid < 64) tok[tid] = seq[tid * SEQ + s];   // seq layout [B][S]
    __syncthreads();

    const int tx = tid & 15;   // b groups: b = tx + 16*ib
    const int ty = tid >> 4;   // r groups: r_local = ty + 16*jr

    float acc[4][16];
#pragma unroll
    for (int ib = 0; ib < 4; ++ib)
#pragma unroll
        for (int jr = 0; jr < 16; ++jr) acc[ib][jr] = 0.f;

    for (int kc = 0; kc < 32; ++kc) {
        // stage A: 64 rows x 32 floats = 512 float4, 2 per thread
#pragma unroll
        for (int it = 0; it < 2; ++it) {
            int f = it * 256 + tid;
            int row = f >> 3, c4 = f & 7;
            const float4 v = *(const float4*)(emb + (size_t)tok[row] * EMBED + kc * 32 + c4 * 4);
            *(float4*)(als + row * 36 + c4 * 4) = v;
        }
        // stage B: 256 rows x 32 floats = 2048 float4, 8 per thread
#pragma unroll
        for (int it = 0; it < 8; ++it) {
            int f = it * 256 + tid;
            int row = f >> 3, c4 = f & 7;
            const float4 v = *(const float4*)(Wih + (size_t)(r0 + row) * EMBED + kc * 32 + c4 * 4);
            *(float4*)(bls + row * 36 + c4 * 4) = v;
        }
        __syncthreads();

#pragma unroll
        for (int kk4 = 0; kk4 < 8; ++kk4) {
            float4 a4[4];
#pragma unroll
            for (int ib = 0; ib < 4; ++ib)
                a4[ib] = *(const float4*)(als + (tx + 16 * ib) * 36 + kk4 * 4);
#pragma unroll
            for (int jr = 0; jr < 16; ++jr) {
                const float4 b4 = *(const float4*)(bls + (ty + 16 * jr) * 36 + kk4 * 4);
#pragma unroll
                for (int ib = 0; ib < 4; ++ib) {
                    acc[ib][jr] += a4[ib].x * b4.x + a4[ib].y * b4.y
                                 + a4[ib].z * b4.z + a4[ib].w * b4.w;
                }
            }
        }
        __syncthreads();
    }

    // epilogue: add biases, store transposed gx[s][r][b]
    float* gxs = gx + (size_t)s * (R4 * BATCH);
#pragma unroll
    for (int jr = 0; jr < 16; ++jr) {
        const int r = r0 + ty + 16 * jr;
        const float bias = bih[r] + bhh[r];
#pragma unroll
        for (int ib = 0; ib < 4; ++ib) {
            gxs[(size_t)r * BATCH + tx + 16 * ib] = acc[ib][jr] + bias;
        }
    }
}

// ---------------------------------------------------------------------------
// Phase B: 512-step LSTM recurrence. Cooperative, 256 blocks x 256 threads.
// Thread owns (b = tid&63, u = blockIdx.x*4 + tid>>6): computes all 4 gates of
// its hidden unit, keeps c in a register for all 512 steps. h double-buffered
// in global (1 grid.sync per step). W_hh rows read via wave-uniform scalar
// pointers; h tile staged in LDS with stride-33-float4 padding.
// ---------------------------------------------------------------------------
__global__ __launch_bounds__(256) void lstm_kernel(
    const float* __restrict__ gx, const float* __restrict__ Whh,
    float* __restrict__ h0buf, float* __restrict__ h1buf,
    float* __restrict__ out)
{
    cg::grid_group grid = cg::this_grid();
    __shared__ float hlds[64 * 132];   // 64 b-rows x 128 k, stride 132 floats (33 f4)

    const int tid = threadIdx.x;
    const int b   = tid & 63;
    const int du  = __builtin_amdgcn_readfirstlane(tid >> 6);  // wave-uniform
    const int u   = blockIdx.x * 4 + du;

    const float* w0 = Whh + (size_t)(0 * HID + u) * HID;
    const float* w1 = Whh + (size_t)(1 * HID + u) * HID;
    const float* w2 = Whh + (size_t)(2 * HID + u) * HID;
    const float* w3 = Whh + (size_t)(3 * HID + u) * HID;

    float c = 0.f, hval = 0.f;
    h0buf[(size_t)b * HID + u] = 0.f;   // h0 = 0 (ws is poisoned, must init)
    grid.sync();

    for (int s = 0; s < SEQ; ++s) {
        const float* hb = (s & 1) ? h1buf : h0buf;
        float*       hn = (s & 1) ? h0buf : h1buf;
        const float* gxs = gx + (size_t)s * (R4 * BATCH);

        float a0 = gxs[(size_t)(0 * HID + u) * BATCH + b];
        float a1 = gxs[(size_t)(1 * HID + u) * BATCH + b];
        float a2 = gxs[(size_t)(2 * HID + u) * BATCH + b];
        float a3 = gxs[(size_t)(3 * HID + u) * BATCH + b];

        for (int kc = 0; kc < 8; ++kc) {
            // stage h chunk: 64 x 128 floats = 2048 float4, 8 per thread
#pragma unroll
            for (int it = 0; it < 8; ++it) {
                int f = it * 256 + tid;
                int row = f >> 5, c4 = f & 31;
                const float4 v = *(const float4*)(hb + (size_t)row * HID + kc * 128 + c4 * 4);
                *(float4*)(hlds + row * 132 + c4 * 4) = v;
            }
            __syncthreads();

            const float* hrow = hlds + b * 132;
            const float* w0c = w0 + kc * 128;
            const float* w1c = w1 + kc * 128;
            const float* w2c = w2 + kc * 128;
            const float* w3c = w3 + kc * 128;
#pragma unroll
            for (int kk4 = 0; kk4 < 32; ++kk4) {
                const float4 hv  = *(const float4*)(hrow + kk4 * 4);
                const float4 v0  = *(const float4*)(w0c + kk4 * 4);
                const float4 v1  = *(const float4*)(w1c + kk4 * 4);
                const float4 v2  = *(const float4*)(w2c + kk4 * 4);
                const float4 v3  = *(const float4*)(w3c + kk4 * 4);
                a0 += hv.x * v0.x + hv.y * v0.y + hv.z * v0.z + hv.w * v0.w;
                a1 += hv.x * v1.x + hv.y * v1.y + hv.z * v1.z + hv.w * v1.w;
                a2 += hv.x * v2.x + hv.y * v2.y + hv.z * v2.z + hv.w * v2.w;
                a3 += hv.x * v3.x + hv.y * v3.y + hv.z * v3.z + hv.w * v3.w;
            }
            __syncthreads();
        }

        // cell update (i, f, g, o order matches torch LSTMCell / reference split)
        const float ig = 1.f / (1.f + expf(-a0));
        const float fg = 1.f / (1.f + expf(-a1));
        const float gg = tanhf(a2);
        const float og = 1.f / (1.f + expf(-a3));
        c = fg * c + ig * gg;
        hval = og * tanhf(c);

        hn[(size_t)b * HID + u] = hval;
        out[((size_t)b * SEQ + s) * HID + u] = hval;   // encoder_outputs [B][S][H]
        grid.sync();
    }

    float* hlast = out + (size_t)BATCH * SEQ * HID;
    float* clast = hlast + (size_t)BATCH * HID;
    hlast[(size_t)b * HID + u] = hval;
    clast[(size_t)b * HID + u] = c;
}

// ---------------------------------------------------------------------------
extern "C" void kernel_launch(void* const* d_in, const int* in_sizes, int n_in,
                              void* d_out, int out_size, void* d_ws, size_t ws_size,
                              hipStream_t stream)
{
    const float* emb = (const float*)d_in[0];   // [32000,1024]
    const float* Wih = (const float*)d_in[1];   // [4096,1024]
    const float* Whh = (const float*)d_in[2];   // [4096,1024]
    const float* bih = (const float*)d_in[3];   // [4096]
    const float* bhh = (const float*)d_in[4];   // [4096]
    const int*   seq = (const int*)d_in[5];     // [64,512]
    float* out = (float*)d_out;

    // workspace layout: gx [512][4096][64] fp32 (536.9 MB) + two h buffers
    float* gx = (float*)d_ws;
    float* h0 = gx + (size_t)SEQ * R4 * BATCH;
    float* h1 = h0 + (size_t)BATCH * HID;

    dim3 gA(16, 512);
    gates_x_kernel<<<gA, 256, 0, stream>>>(emb, Wih, bih, bhh, seq, gx);

    void* args[] = { (void*)&gx, (void*)&Whh, (void*)&h0, (void*)&h1, (void*)&out };
    hipLaunchCooperativeKernel((void*)lstm_kernel, dim3(256), dim3(256), args, 0, stream);
}

// Round 2
// 20168.324 us; speedup vs baseline: 2.7531x; 2.7531x over previous
//
#include <hip/hip_runtime.h>
#include <hip/hip_cooperative_groups.h>

namespace cg = cooperative_groups;

#define VOCAB 32000
#define EMBED 1024
#define HID   1024
#define BATCH 64
#define SEQ   512
#define R4    4096   // 4*HID gate rows (i,f,g,o)

typedef float floatx4 __attribute__((ext_vector_type(4)));
typedef short bf16x8  __attribute__((ext_vector_type(8)));   // 8 bf16 = 4 VGPRs (guide §3)

// fp32 -> bf16 round-to-nearest-even
static __device__ __forceinline__ unsigned short f2bf(float x) {
    unsigned int u = __float_as_uint(x);
    u = (u + 0x7FFFu + ((u >> 16) & 1u)) >> 16;
    return (unsigned short)u;
}

// load 8 contiguous fp32, convert to bf16x8 fragment
static __device__ __forceinline__ bf16x8 cvt8(const float* p) {
    float4 a = ((const float4*)p)[0];
    float4 b = ((const float4*)p)[1];
    bf16x8 r;
    r[0] = (short)f2bf(a.x); r[1] = (short)f2bf(a.y);
    r[2] = (short)f2bf(a.z); r[3] = (short)f2bf(a.w);
    r[4] = (short)f2bf(b.x); r[5] = (short)f2bf(b.y);
    r[6] = (short)f2bf(b.z); r[7] = (short)f2bf(b.w);
    return r;
}

// ---------------------------------------------------------------------------
// Phase A: gx[s][r][b] = emb[seq[b][s]] . W_ih[r] + b_ih[r] + b_hh[r]  (fp32 out)
// grid (512 s, 32 rtiles), 256 threads. Block tile: M=64 batches, N=128 rows,
// K=1024. A (emb gather) staged to LDS as bf16 per 128-K chunk; B (W_ih)
// converted fp32->bf16 in-register on the fly. mfma_f32_16x16x32_bf16.
// A-frag layout: A[m=lane&15][k=(lane>>4)*8+j]; B-frag symmetric on n.
// C/D: col(n)=lane&15, row(m)=(lane>>4)*4+reg  (m = batch here).
// ---------------------------------------------------------------------------
__global__ __launch_bounds__(256) void gates_x_mfma(
    const float* __restrict__ emb, const float* __restrict__ Wih,
    const float* __restrict__ bih, const float* __restrict__ bhh,
    const int* __restrict__ seq, float* __restrict__ gx)
{
    __shared__ unsigned short Als[64 * 136];   // 64 rows x 128 k bf16, stride 136 (odd 16B granule -> 2-way)
    __shared__ int tok[64];

    const int tid = threadIdx.x;
    const int s   = blockIdx.x;
    const int r0  = blockIdx.y * 128;

    if (tid < 64) tok[tid] = seq[tid * SEQ + s];
    __syncthreads();

    const int w   = tid >> 6;   // wave 0..3 -> rows [r0+32w, r0+32w+32)
    const int l   = tid & 63;
    const int l16 = l & 15;
    const int kq  = l >> 4;

    const float* wrow0 = Wih + (size_t)(r0 + 32 * w + l16) * EMBED;
    const float* wrow1 = wrow0 + 16 * EMBED;

    floatx4 acc[4][2];
#pragma unroll
    for (int mt = 0; mt < 4; ++mt)
#pragma unroll
        for (int nt = 0; nt < 2; ++nt)
            acc[mt][nt] = (floatx4){0.f, 0.f, 0.f, 0.f};

    const int arow  = tid >> 2;  // staging: 4 threads per row, 32 floats each
    const int apart = tid & 3;
    const float* asrc_base = emb + (size_t)tok[arow] * EMBED + apart * 32;
    unsigned short* adst = Als + arow * 136 + apart * 32;

    for (int kb = 0; kb < EMBED; kb += 128) {
        const float* asrc = asrc_base + kb;
#pragma unroll
        for (int j = 0; j < 4; ++j)
            *(bf16x8*)(adst + j * 8) = cvt8(asrc + j * 8);
        __syncthreads();

#pragma unroll
        for (int kc = 0; kc < 4; ++kc) {
            const int ko = kb + kc * 32 + kq * 8;
            const bf16x8 b0 = cvt8(wrow0 + ko);
            const bf16x8 b1 = cvt8(wrow1 + ko);
#pragma unroll
            for (int mt = 0; mt < 4; ++mt) {
                const bf16x8 af = *(const bf16x8*)(Als + (mt * 16 + l16) * 136 + kc * 32 + kq * 8);
                acc[mt][0] = __builtin_amdgcn_mfma_f32_16x16x32_bf16(af, b0, acc[mt][0], 0, 0, 0);
                acc[mt][1] = __builtin_amdgcn_mfma_f32_16x16x32_bf16(af, b1, acc[mt][1], 0, 0, 0);
            }
        }
        __syncthreads();
    }

    // epilogue: add biases, store fp32 gx[s][r][b] (contiguous along b, float4)
    const int rA = r0 + 32 * w + l16;
    const float bv0 = bih[rA] + bhh[rA];
    const float bv1 = bih[rA + 16] + bhh[rA + 16];
    float* gxs = gx + (size_t)s * (R4 * BATCH);
#pragma unroll
    for (int nt = 0; nt < 2; ++nt) {
        const float bv = nt ? bv1 : bv0;
        const int r = rA + 16 * nt;
#pragma unroll
        for (int mt = 0; mt < 4; ++mt) {
            float4 v;
            v.x = acc[mt][nt][0] + bv;
            v.y = acc[mt][nt][1] + bv;
            v.z = acc[mt][nt][2] + bv;
            v.w = acc[mt][nt][3] + bv;
            *(float4*)(gxs + (size_t)r * BATCH + mt * 16 + kq * 4) = v;   // b = mt*16 + kq*4 + reg
        }
    }
}

// ---------------------------------------------------------------------------
// Phase B: persistent LSTM. 256 blocks x 256 thr (cooperative). Block owns
// 4 units u0..u0+3 = 16 W_hh rows (ordered m = gate*4 + ulocal), held in LDS
// as bf16 for all 512 steps. Per step: wave w computes the 16x16 gate tile
// for batches [16w,16w+16) with 32 MFMAs; B-frags load h directly from the
// global bf16 h buffer (lane reads 16B contiguous of h[b][:], coalesced).
// D staged via LDS -> thread (u=wave, b=lane) applies nonlinearities; c lives
// in a register all 512 steps. Double-buffered h, one grid.sync per step.
// ---------------------------------------------------------------------------
__global__ __launch_bounds__(256) void lstm_mfma(
    const float* __restrict__ gx, const float* __restrict__ Whh,
    unsigned short* __restrict__ h0buf, unsigned short* __restrict__ h1buf,
    float* __restrict__ out)
{
    cg::grid_group grid = cg::this_grid();
    __shared__ unsigned short Wlds[16 * 1032];  // 16 rows x 1024 bf16, stride 1032 (2-way LDS aliasing only)
    __shared__ float Slds[16 * 66];             // D staging [m=16][b=64] fp32, pad 66

    const int tid = threadIdx.x;
    const int w   = tid >> 6;
    const int l   = tid & 63;
    const int l16 = l & 15;
    const int kq  = l >> 4;
    const int u0  = blockIdx.x * 4;

    // one-time: stage this block's 16 W_hh rows to LDS as bf16
    {
        const int m = tid >> 4;       // 0..15 : m = gate*4 + ulocal
        const int p = tid & 15;       // 16 threads/row, 64 floats each
        const int gate = m >> 2, ulm = m & 3;
        const float* src = Whh + (size_t)(gate * HID + u0 + ulm) * HID + p * 64;
        unsigned short* dst = Wlds + m * 1032 + p * 64;
#pragma unroll
        for (int j = 0; j < 8; ++j)
            *(bf16x8*)(dst + j * 8) = cvt8(src + j * 8);
    }

    const int ul = w;       // wave id = unit-local (4 waves = 4 units)
    const int b  = l;       // lane = batch
    const int u  = u0 + ul;

    float c = 0.f, hval = 0.f;
    h0buf[(size_t)b * HID + u] = 0;   // h0 = 0 (ws poisoned)
    __syncthreads();
    grid.sync();

    const unsigned short* wbase = Wlds + l16 * 1032 + kq * 8;   // A-frag: m=l16

    for (int s = 0; s < SEQ; ++s) {
        const unsigned short* hb = (s & 1) ? h1buf : h0buf;
        unsigned short*       hn = (s & 1) ? h0buf : h1buf;
        const float* gxs = gx + (size_t)s * (R4 * BATCH);

        // hoist gx loads (independent of MFMA chain)
        const float gxi = gxs[(size_t)(0 * HID + u) * BATCH + b];
        const float gxf = gxs[(size_t)(1 * HID + u) * BATCH + b];
        const float gxg = gxs[(size_t)(2 * HID + u) * BATCH + b];
        const float gxo = gxs[(size_t)(3 * HID + u) * BATCH + b];

        // B-frag: n = batch 16w+l16, k contiguous -> 16B loads, 16 full lines/wave
        const unsigned short* hbase = hb + (size_t)(16 * w + l16) * HID + kq * 8;

        floatx4 acc = (floatx4){0.f, 0.f, 0.f, 0.f};
#pragma unroll 16
        for (int kc = 0; kc < 32; ++kc) {
            const bf16x8 bfrag = *(const bf16x8*)(hbase + kc * 32);
            const bf16x8 afrag = *(const bf16x8*)(wbase + kc * 32);
            acc = __builtin_amdgcn_mfma_f32_16x16x32_bf16(afrag, bfrag, acc, 0, 0, 0);
        }

        // D: m = kq*4+reg, n = 16w+l16
#pragma unroll
        for (int r = 0; r < 4; ++r)
            Slds[(kq * 4 + r) * 66 + 16 * w + l16] = acc[r];
        __syncthreads();

        const float pi = Slds[(0 * 4 + ul) * 66 + b] + gxi;
        const float pf = Slds[(1 * 4 + ul) * 66 + b] + gxf;
        const float pg = Slds[(2 * 4 + ul) * 66 + b] + gxg;
        const float po = Slds[(3 * 4 + ul) * 66 + b] + gxo;

        const float ig = 1.f / (1.f + __expf(-pi));
        const float fg = 1.f / (1.f + __expf(-pf));
        const float gg = 2.f / (1.f + __expf(-2.f * pg)) - 1.f;   // tanh
        const float og = 1.f / (1.f + __expf(-po));
        c = fg * c + ig * gg;
        const float th = 2.f / (1.f + __expf(-2.f * c)) - 1.f;
        hval = og * th;

        hn[(size_t)b * HID + u] = f2bf(hval);
        out[((size_t)b * SEQ + s) * HID + u] = hval;
        grid.sync();   // also orders Slds read -> next-step write
    }

    float* hlast = out + (size_t)BATCH * SEQ * HID;
    float* clast = hlast + (size_t)BATCH * HID;
    hlast[(size_t)b * HID + u] = hval;
    clast[(size_t)b * HID + u] = c;
}

// ---------------------------------------------------------------------------
extern "C" void kernel_launch(void* const* d_in, const int* in_sizes, int n_in,
                              void* d_out, int out_size, void* d_ws, size_t ws_size,
                              hipStream_t stream)
{
    const float* emb = (const float*)d_in[0];
    const float* Wih = (const float*)d_in[1];
    const float* Whh = (const float*)d_in[2];
    const float* bih = (const float*)d_in[3];
    const float* bhh = (const float*)d_in[4];
    const int*   seq = (const int*)d_in[5];
    float* out = (float*)d_out;

    // ws: gx fp32 [512][4096][64] (536.9 MB, same footprint as round 1) + 2 bf16 h buffers
    float* gx = (float*)d_ws;
    unsigned short* h0 = (unsigned short*)(gx + (size_t)SEQ * R4 * BATCH);
    unsigned short* h1 = h0 + (size_t)BATCH * HID;

    dim3 gA(512, 32);   // x = s (stripes XCDs), y = rtile (W slice stays L2-resident per XCD)
    gates_x_mfma<<<gA, 256, 0, stream>>>(emb, Wih, bih, bhh, seq, gx);

    void* args[] = { (void*)&gx, (void*)&Whh, (void*)&h0, (void*)&h1, (void*)&out };
    hipLaunchCooperativeKernel((void*)lstm_mfma, dim3(256), dim3(256), args, 0, stream);
}